// Round 1
// baseline (302.148 us; speedup 1.0000x reference)
//
#include <hip/hip_runtime.h>
#include <cstdint>
#include <cstddef>

typedef __bf16 bf16x8_t __attribute__((ext_vector_type(8)));
typedef float f32x4_t __attribute__((ext_vector_type(4)));

#define SCALE 0.3535533905932738f
#define NEG -1000000000.0f

__device__ __forceinline__ unsigned short f2b(float f) {
    unsigned int u = __builtin_bit_cast(unsigned int, f);
    u += 0x7FFFu + ((u >> 16) & 1u);   // round-to-nearest-even
    return (unsigned short)(u >> 16);
}

// ---------------- fp32 -> bf16 convert, 4 elems/thread ----------------
__global__ __launch_bounds__(256) void cvt_kernel(const float* __restrict__ in,
                                                  unsigned short* __restrict__ out,
                                                  int n4) {
    int i = blockIdx.x * 256 + threadIdx.x;
    if (i >= n4) return;
    const float4 f = reinterpret_cast<const float4*>(in)[i];
    ushort4 o;
    o.x = f2b(f.x); o.y = f2b(f.y); o.z = f2b(f.z); o.w = f2b(f.w);
    reinterpret_cast<ushort4*>(out)[i] = o;
}

// ---------------- GEMM1: qkv = A @ W^T + b, scatter to heads ----------------
// A [24576][512] bf16, W [1536][512] bf16 (row = output col, K-major)
__global__ __launch_bounds__(256) void gemm_qkv(
    const unsigned short* __restrict__ A,
    const unsigned short* __restrict__ W,
    const float* __restrict__ bias,
    unsigned short* __restrict__ qb,   // [48][8][512][64], pre-scaled
    unsigned short* __restrict__ kb,   // [48][8][512][64]
    unsigned short* __restrict__ vT)   // [48][8][64][512] (transposed)
{
    __shared__ unsigned short As[128*64];
    __shared__ unsigned short Bs[128*64];
    const int tid = threadIdx.x;
    const int lane = tid & 63;
    const int l15 = lane & 15, lhi = lane >> 4;
    const int wid = tid >> 6, wr = wid >> 1, wc = wid & 1;
    const int m0 = blockIdx.y * 128, n0 = blockIdx.x * 128;

    f32x4_t acc[4][4] = {};

    for (int k0 = 0; k0 < 512; k0 += 64) {
        __syncthreads();
#pragma unroll
        for (int it = 0; it < 4; ++it) {
            const int e = (it*256 + tid) * 8;
            const int r = e >> 6, c = e & 63;
            *reinterpret_cast<uint4*>(&As[r*64+c]) =
                *reinterpret_cast<const uint4*>(&A[(size_t)(m0+r)*512 + k0 + c]);
            *reinterpret_cast<uint4*>(&Bs[r*64+c]) =
                *reinterpret_cast<const uint4*>(&W[(size_t)(n0+r)*512 + k0 + c]);
        }
        __syncthreads();
#pragma unroll
        for (int kk = 0; kk < 2; ++kk) {
            bf16x8_t af[4], bfr[4];
#pragma unroll
            for (int x = 0; x < 4; ++x) {
                af[x]  = *reinterpret_cast<const bf16x8_t*>(&As[(wr*64 + x*16 + l15)*64 + kk*32 + lhi*8]);
                bfr[x] = *reinterpret_cast<const bf16x8_t*>(&Bs[(wc*64 + x*16 + l15)*64 + kk*32 + lhi*8]);
            }
#pragma unroll
            for (int mi = 0; mi < 4; ++mi)
#pragma unroll
                for (int nj = 0; nj < 4; ++nj)
                    acc[mi][nj] = __builtin_amdgcn_mfma_f32_16x16x32_bf16(af[mi], bfr[nj], acc[mi][nj], 0, 0, 0);
        }
    }

#pragma unroll
    for (int mi = 0; mi < 4; ++mi) {
#pragma unroll
        for (int nj = 0; nj < 4; ++nj) {
            const int gn = n0 + wc*64 + nj*16 + l15;
            const float bi = bias[gn];
            const int which = gn >> 9, hh = (gn >> 6) & 7, dh = gn & 63;
#pragma unroll
            for (int i = 0; i < 4; ++i) {
                const int gm = m0 + wr*64 + mi*16 + lhi*4 + i;
                const int bt = gm >> 9, row = gm & 511;
                const float v = acc[mi][nj][i] + bi;
                const size_t ho = (size_t)bt*8 + hh;
                if (which == 0)      qb[ho*(512*64) + (size_t)row*64 + dh] = f2b(v * SCALE);
                else if (which == 1) kb[ho*(512*64) + (size_t)row*64 + dh] = f2b(v);
                else                 vT[ho*(64*512) + (size_t)dh*512 + row] = f2b(v);
            }
        }
    }
}

// ---------------- fused masked flash attention per (bt, h, qtile) ----------------
__global__ __launch_bounds__(256) void attn_kernel(
    const unsigned short* __restrict__ qb,
    const unsigned short* __restrict__ kb,
    const unsigned short* __restrict__ vT,
    const int* __restrict__ Mm,
    unsigned short* __restrict__ ob)   // [24576][512] bf16
{
    __shared__ unsigned short Ks[64*64];
    __shared__ unsigned short Vs[64*64];        // already [dh][k]
    __shared__ unsigned short Ps[4][32*64];

    const int tid = threadIdx.x;
    const int lane = tid & 63;
    const int w = tid >> 6;
    const int l15 = lane & 15, lhi = lane >> 4;
    const int qt = blockIdx.x, h = blockIdx.y, bt = blockIdx.z;
    const int q0 = qt*128 + w*32;
    const size_t hoQK = ((size_t)bt*8 + h) * (512*64);
    const size_t hoV  = ((size_t)bt*8 + h) * (64*512);

    bf16x8_t qf[2][2];
#pragma unroll
    for (int mi = 0; mi < 2; ++mi)
#pragma unroll
        for (int kk = 0; kk < 2; ++kk)
            qf[mi][kk] = *reinterpret_cast<const bf16x8_t*>(
                &qb[hoQK + (size_t)(q0 + mi*16 + l15)*64 + kk*32 + lhi*8]);

    f32x4_t of[2][4] = {};
    float mrow[2][4], lrow[2][4];
#pragma unroll
    for (int mi = 0; mi < 2; ++mi)
#pragma unroll
        for (int i = 0; i < 4; ++i) { mrow[mi][i] = -1e30f; lrow[mi][i] = 0.f; }

    for (int kbk = 0; kbk < 8; ++kbk) {
        __syncthreads();
#pragma unroll
        for (int it = 0; it < 2; ++it) {
            const int e = (it*256 + tid) * 8;
            const int r = e >> 6, c = e & 63;
            *reinterpret_cast<uint4*>(&Ks[r*64+c]) =
                *reinterpret_cast<const uint4*>(&kb[hoQK + (size_t)(kbk*64 + r)*64 + c]);
            *reinterpret_cast<uint4*>(&Vs[r*64+c]) =
                *reinterpret_cast<const uint4*>(&vT[hoV + (size_t)r*512 + kbk*64 + c]);
        }
        __syncthreads();

        // S = Q K^T   (scale pre-folded into q)
        f32x4_t sa[2][4] = {};
#pragma unroll
        for (int kk = 0; kk < 2; ++kk) {
            bf16x8_t kf[4];
#pragma unroll
            for (int nj = 0; nj < 4; ++nj)
                kf[nj] = *reinterpret_cast<const bf16x8_t*>(&Ks[(nj*16 + l15)*64 + kk*32 + lhi*8]);
#pragma unroll
            for (int mi = 0; mi < 2; ++mi)
#pragma unroll
                for (int nj = 0; nj < 4; ++nj)
                    sa[mi][nj] = __builtin_amdgcn_mfma_f32_16x16x32_bf16(qf[mi][kk], kf[nj], sa[mi][nj], 0, 0, 0);
        }

        // mask + per-row tile max
        float tmax[2][4];
#pragma unroll
        for (int mi = 0; mi < 2; ++mi)
#pragma unroll
            for (int i = 0; i < 4; ++i) tmax[mi][i] = -1e30f;

#pragma unroll
        for (int mi = 0; mi < 2; ++mi) {
#pragma unroll
            for (int i = 0; i < 4; ++i) {
                const int qrow = q0 + mi*16 + lhi*4 + i;
                const size_t mbase = ((size_t)bt*512 + qrow)*512 + kbk*64 + l15;
#pragma unroll
                for (int nj = 0; nj < 4; ++nj) {
                    const int mv = Mm[mbase + nj*16];
                    const float s = sa[mi][nj][i] + (float)mv * NEG;
                    sa[mi][nj][i] = s;
                    tmax[mi][i] = fmaxf(tmax[mi][i], s);
                }
            }
        }
#pragma unroll
        for (int d = 1; d < 16; d <<= 1)
#pragma unroll
            for (int mi = 0; mi < 2; ++mi)
#pragma unroll
                for (int i = 0; i < 4; ++i)
                    tmax[mi][i] = fmaxf(tmax[mi][i], __shfl_xor(tmax[mi][i], d));

        float corr[2][4], rs[2][4];
#pragma unroll
        for (int mi = 0; mi < 2; ++mi)
#pragma unroll
            for (int i = 0; i < 4; ++i) {
                const float mn = fmaxf(mrow[mi][i], tmax[mi][i]);
                corr[mi][i] = __expf(mrow[mi][i] - mn);
                mrow[mi][i] = mn;
                rs[mi][i] = 0.f;
            }

#pragma unroll
        for (int mi = 0; mi < 2; ++mi)
#pragma unroll
            for (int nj = 0; nj < 4; ++nj)
#pragma unroll
                for (int i = 0; i < 4; ++i) {
                    const float p = __expf(sa[mi][nj][i] - mrow[mi][i]);
                    sa[mi][nj][i] = p;
                    rs[mi][i] += p;
                }
#pragma unroll
        for (int d = 1; d < 16; d <<= 1)
#pragma unroll
            for (int mi = 0; mi < 2; ++mi)
#pragma unroll
                for (int i = 0; i < 4; ++i)
                    rs[mi][i] += __shfl_xor(rs[mi][i], d);

#pragma unroll
        for (int mi = 0; mi < 2; ++mi)
#pragma unroll
            for (int i = 0; i < 4; ++i)
                lrow[mi][i] = lrow[mi][i]*corr[mi][i] + rs[mi][i];

#pragma unroll
        for (int mi = 0; mi < 2; ++mi)
#pragma unroll
            for (int dj = 0; dj < 4; ++dj)
#pragma unroll
                for (int i = 0; i < 4; ++i)
                    of[mi][dj][i] *= corr[mi][i];

        // P -> LDS (C-layout) then re-read as A-fragments
#pragma unroll
        for (int mi = 0; mi < 2; ++mi)
#pragma unroll
            for (int nj = 0; nj < 4; ++nj)
#pragma unroll
                for (int i = 0; i < 4; ++i)
                    Ps[w][(mi*16 + lhi*4 + i)*64 + nj*16 + l15] = f2b(sa[mi][nj][i]);

        bf16x8_t pf[2][2];
#pragma unroll
        for (int mi = 0; mi < 2; ++mi)
#pragma unroll
            for (int kk = 0; kk < 2; ++kk)
                pf[mi][kk] = *reinterpret_cast<const bf16x8_t*>(&Ps[w][(mi*16 + l15)*64 + kk*32 + lhi*8]);

#pragma unroll
        for (int kk = 0; kk < 2; ++kk) {
            bf16x8_t vf[4];
#pragma unroll
            for (int dj = 0; dj < 4; ++dj)
                vf[dj] = *reinterpret_cast<const bf16x8_t*>(&Vs[(dj*16 + l15)*64 + kk*32 + lhi*8]);
#pragma unroll
            for (int mi = 0; mi < 2; ++mi)
#pragma unroll
                for (int dj = 0; dj < 4; ++dj)
                    of[mi][dj] = __builtin_amdgcn_mfma_f32_16x16x32_bf16(pf[mi][kk], vf[dj], of[mi][dj], 0, 0, 0);
        }
    }

#pragma unroll
    for (int mi = 0; mi < 2; ++mi)
#pragma unroll
        for (int i = 0; i < 4; ++i) {
            const int qrow = q0 + mi*16 + lhi*4 + i;
            const float inv = 1.f / lrow[mi][i];
#pragma unroll
            for (int dj = 0; dj < 4; ++dj)
                ob[((size_t)bt*512 + qrow)*512 + h*64 + dj*16 + l15] = f2b(of[mi][dj][i] * inv);
        }
}

// ---------------- GEMM2: out = A @ Wo^T + b (fp32 out) ----------------
__global__ __launch_bounds__(256) void gemm_out(
    const unsigned short* __restrict__ A,   // [24576][512] bf16
    const unsigned short* __restrict__ W,   // [512][512] bf16
    const float* __restrict__ bias,
    float* __restrict__ out)
{
    __shared__ unsigned short As[128*64];
    __shared__ unsigned short Bs[128*64];
    const int tid = threadIdx.x;
    const int lane = tid & 63;
    const int l15 = lane & 15, lhi = lane >> 4;
    const int wid = tid >> 6, wr = wid >> 1, wc = wid & 1;
    const int m0 = blockIdx.y * 128, n0 = blockIdx.x * 128;

    f32x4_t acc[4][4] = {};

    for (int k0 = 0; k0 < 512; k0 += 64) {
        __syncthreads();
#pragma unroll
        for (int it = 0; it < 4; ++it) {
            const int e = (it*256 + tid) * 8;
            const int r = e >> 6, c = e & 63;
            *reinterpret_cast<uint4*>(&As[r*64+c]) =
                *reinterpret_cast<const uint4*>(&A[(size_t)(m0+r)*512 + k0 + c]);
            *reinterpret_cast<uint4*>(&Bs[r*64+c]) =
                *reinterpret_cast<const uint4*>(&W[(size_t)(n0+r)*512 + k0 + c]);
        }
        __syncthreads();
#pragma unroll
        for (int kk = 0; kk < 2; ++kk) {
            bf16x8_t af[4], bfr[4];
#pragma unroll
            for (int x = 0; x < 4; ++x) {
                af[x]  = *reinterpret_cast<const bf16x8_t*>(&As[(wr*64 + x*16 + l15)*64 + kk*32 + lhi*8]);
                bfr[x] = *reinterpret_cast<const bf16x8_t*>(&Bs[(wc*64 + x*16 + l15)*64 + kk*32 + lhi*8]);
            }
#pragma unroll
            for (int mi = 0; mi < 4; ++mi)
#pragma unroll
                for (int nj = 0; nj < 4; ++nj)
                    acc[mi][nj] = __builtin_amdgcn_mfma_f32_16x16x32_bf16(af[mi], bfr[nj], acc[mi][nj], 0, 0, 0);
        }
    }

#pragma unroll
    for (int mi = 0; mi < 4; ++mi) {
#pragma unroll
        for (int nj = 0; nj < 4; ++nj) {
            const int gn = n0 + wc*64 + nj*16 + l15;
            const float bi = bias[gn];
#pragma unroll
            for (int i = 0; i < 4; ++i) {
                const int gm = m0 + wr*64 + mi*16 + lhi*4 + i;
                out[(size_t)gm*512 + gn] = acc[mi][nj][i] + bi;
            }
        }
    }
}

extern "C" void kernel_launch(void* const* d_in, const int* in_sizes, int n_in,
                              void* d_out, int out_size, void* d_ws, size_t ws_size,
                              hipStream_t stream) {
    (void)in_sizes; (void)n_in; (void)out_size; (void)ws_size;
    // setup_inputs order: V, K, Q, M, wx_w, wx_b, wo_w, wo_b  (V,K unused by reference)
    const float* Qin = (const float*)d_in[2];
    const int*   Mm  = (const int*)d_in[3];
    const float* wxw = (const float*)d_in[4];
    const float* wxb = (const float*)d_in[5];
    const float* wow = (const float*)d_in[6];
    const float* wob = (const float*)d_in[7];
    float* out = (float*)d_out;

    char* ws = (char*)d_ws;
    const size_t SZ_A  = (size_t)24576*512*2;   // Q bf16 / attn-out bf16 (reused)
    const size_t SZ_WX = (size_t)1536*512*2;
    const size_t SZ_WO = (size_t)512*512*2;
    const size_t SZ_H  = (size_t)48*8*512*64*2; // per q/k/vT buffer

    unsigned short* Abf  = (unsigned short*)(ws);
    unsigned short* Wxb  = (unsigned short*)(ws + SZ_A);
    unsigned short* Wob  = (unsigned short*)(ws + SZ_A + SZ_WX);
    unsigned short* qb   = (unsigned short*)(ws + SZ_A + SZ_WX + SZ_WO);
    unsigned short* kbuf = (unsigned short*)(ws + SZ_A + SZ_WX + SZ_WO + SZ_H);
    unsigned short* vT   = (unsigned short*)(ws + SZ_A + SZ_WX + SZ_WO + 2*SZ_H);
    unsigned short* attn = Abf;  // reuse: GEMM1 is done with Abf before attention writes

    cvt_kernel<<<(24576*512/4)/256, 256, 0, stream>>>(Qin, Abf, 24576*512/4);
    cvt_kernel<<<(1536*512/4)/256, 256, 0, stream>>>(wxw, Wxb, 1536*512/4);
    cvt_kernel<<<(512*512/4)/256, 256, 0, stream>>>(wow, Wob, 512*512/4);

    gemm_qkv<<<dim3(12, 192), 256, 0, stream>>>(Abf, Wxb, wxb, qb, kbuf, vT);
    attn_kernel<<<dim3(4, 8, 48), 256, 0, stream>>>(qb, kbuf, vT, Mm, attn);
    gemm_out<<<dim3(4, 192), 256, 0, stream>>>(attn, Wob, wob, out);
}

// Round 2
// 245.561 us; speedup vs baseline: 1.2304x; 1.2304x over previous
//
#include <hip/hip_runtime.h>
#include <cstdint>
#include <cstddef>

typedef __bf16 bf16x8_t __attribute__((ext_vector_type(8)));
typedef float f32x4_t __attribute__((ext_vector_type(4)));

#define SCALE 0.3535533905932738f
#define NEG -1000000000.0f

__device__ __forceinline__ unsigned short f2b(float f) {
    unsigned int u = __builtin_bit_cast(unsigned int, f);
    u += 0x7FFFu + ((u >> 16) & 1u);   // round-to-nearest-even
    return (unsigned short)(u >> 16);
}

// swizzled LDS address (in shorts) for [*][64-short] tiles:
// logical (row, col) lives at row*64 + ((col/8) ^ (row&7))*8 + col%8
__device__ __forceinline__ int swz(int row, int chunk) {
    return row * 64 + (((chunk ^ (row & 7)) << 3));
}

// async global->LDS, 16B per lane; dest must be wave-uniform base (HW adds lane*16)
__device__ __forceinline__ void gld16(const void* g, void* l) {
    __builtin_amdgcn_global_load_lds(
        (const __attribute__((address_space(1))) unsigned int*)g,
        (__attribute__((address_space(3))) unsigned int*)l,
        16, 0, 0);
}

// ---------------- fp32 -> bf16 convert, 4 elems/thread ----------------
__global__ __launch_bounds__(256) void cvt_kernel(const float* __restrict__ in,
                                                  unsigned short* __restrict__ out,
                                                  int n4) {
    int i = blockIdx.x * 256 + threadIdx.x;
    if (i >= n4) return;
    const float4 f = reinterpret_cast<const float4*>(in)[i];
    ushort4 o;
    o.x = f2b(f.x); o.y = f2b(f.y); o.z = f2b(f.z); o.w = f2b(f.w);
    reinterpret_cast<ushort4*>(out)[i] = o;
}

// ---------------- GEMM1: qkv = A @ W^T + b, scatter to heads ----------------
__global__ __launch_bounds__(256) void gemm_qkv(
    const unsigned short* __restrict__ A,
    const unsigned short* __restrict__ W,
    const float* __restrict__ bias,
    unsigned short* __restrict__ qb,   // [48][8][512][64], pre-scaled
    unsigned short* __restrict__ kb,   // [48][8][512][64]
    unsigned short* __restrict__ vT)   // [48][8][64][512] (transposed)
{
    __shared__ unsigned short As[128*64];
    __shared__ unsigned short Bs[128*64];
    const int tid = threadIdx.x;
    const int lane = tid & 63;
    const int l15 = lane & 15, lhi = lane >> 4;
    const int wid = tid >> 6, wr = wid >> 1, wc = wid & 1;
    const int m0 = blockIdx.y * 128, n0 = blockIdx.x * 128;
    const int rA = lane >> 3;                 // row-within-8-row stripe
    const int sc = (lane & 7) ^ rA;           // pre-swizzled source chunk

    f32x4_t acc[4][4] = {};

    for (int k0 = 0; k0 < 512; k0 += 64) {
        __syncthreads();   // all waves done reading LDS from previous iter
#pragma unroll
        for (int j = 0; j < 4; ++j) {
            const int ch = 4*wid + j;
            const int gr = ch*8 + rA;         // tile row 0..127
            gld16(&A[(size_t)(m0+gr)*512 + k0 + sc*8], &As[ch*512]);
            gld16(&W[(size_t)(n0+gr)*512 + k0 + sc*8], &Bs[ch*512]);
        }
        asm volatile("s_waitcnt vmcnt(0)" ::: "memory");
        __syncthreads();
#pragma unroll
        for (int kk = 0; kk < 2; ++kk) {
            bf16x8_t af[4], bfr[4];
#pragma unroll
            for (int x = 0; x < 4; ++x) {
                af[x]  = *reinterpret_cast<const bf16x8_t*>(&As[swz(wr*64 + x*16 + l15, kk*4 + lhi)]);
                bfr[x] = *reinterpret_cast<const bf16x8_t*>(&Bs[swz(wc*64 + x*16 + l15, kk*4 + lhi)]);
            }
#pragma unroll
            for (int mi = 0; mi < 4; ++mi)
#pragma unroll
                for (int nj = 0; nj < 4; ++nj)
                    acc[mi][nj] = __builtin_amdgcn_mfma_f32_16x16x32_bf16(af[mi], bfr[nj], acc[mi][nj], 0, 0, 0);
        }
    }

#pragma unroll
    for (int mi = 0; mi < 4; ++mi) {
#pragma unroll
        for (int nj = 0; nj < 4; ++nj) {
            const int gn = n0 + wc*64 + nj*16 + l15;
            const float bi = bias[gn];
            const int which = gn >> 9, hh = (gn >> 6) & 7, dh = gn & 63;
#pragma unroll
            for (int i = 0; i < 4; ++i) {
                const int gm = m0 + wr*64 + mi*16 + lhi*4 + i;
                const int bt = gm >> 9, row = gm & 511;
                const float v = acc[mi][nj][i] + bi;
                const size_t ho = (size_t)bt*8 + hh;
                if (which == 0)      qb[ho*(512*64) + (size_t)row*64 + dh] = f2b(v * SCALE);
                else if (which == 1) kb[ho*(512*64) + (size_t)row*64 + dh] = f2b(v);
                else                 vT[ho*(64*512) + (size_t)dh*512 + row] = f2b(v);
            }
        }
    }
}

// ---------------- fused masked flash attention per (bt, h, qtile) ----------------
__global__ __launch_bounds__(256) void attn_kernel(
    const unsigned short* __restrict__ qb,
    const unsigned short* __restrict__ kb,
    const unsigned short* __restrict__ vT,
    const int* __restrict__ Mm,
    unsigned short* __restrict__ ob)   // [24576][512] bf16
{
    __shared__ unsigned short Ks[2][64*64];
    __shared__ unsigned short Vs[2][64*64];   // [dh][k]
    __shared__ unsigned short Ps[4][32*64];

    const int tid = threadIdx.x;
    const int lane = tid & 63;
    const int w = tid >> 6;
    const int l15 = lane & 15, lhi = lane >> 4;
    const int qt = blockIdx.x, h = blockIdx.y, bt = blockIdx.z;
    const int q0 = qt*128 + w*32;
    const size_t hoQK = ((size_t)bt*8 + h) * (512*64);
    const size_t hoV  = ((size_t)bt*8 + h) * (64*512);

    const int rA = lane >> 3;
    const int sc = (lane & 7) ^ rA;
    const int tr0 = (2*w+0)*8 + rA;   // tile rows this wave stages (chunk 2w)
    const int tr1 = (2*w+1)*8 + rA;   // (chunk 2w+1)

    bf16x8_t qf[2][2];
#pragma unroll
    for (int mi = 0; mi < 2; ++mi)
#pragma unroll
        for (int kk = 0; kk < 2; ++kk)
            qf[mi][kk] = *reinterpret_cast<const bf16x8_t*>(
                &qb[hoQK + (size_t)(q0 + mi*16 + l15)*64 + kk*32 + lhi*8]);

    f32x4_t of[2][4] = {};
    float mrow[2][4], lrow[2][4];
#pragma unroll
    for (int mi = 0; mi < 2; ++mi)
#pragma unroll
        for (int i = 0; i < 4; ++i) { mrow[mi][i] = -1e30f; lrow[mi][i] = 0.f; }

    // prologue: stage tile 0 into buf 0
    {
        const int t = 0;
        gld16(&kb[hoQK + (size_t)(t*64 + tr0)*64 + sc*8], &Ks[0][(2*w+0)*512]);
        gld16(&kb[hoQK + (size_t)(t*64 + tr1)*64 + sc*8], &Ks[0][(2*w+1)*512]);
        gld16(&vT[hoV + (size_t)tr0*512 + t*64 + sc*8],   &Vs[0][(2*w+0)*512]);
        gld16(&vT[hoV + (size_t)tr1*512 + t*64 + sc*8],   &Vs[0][(2*w+1)*512]);
    }

    for (int kbk = 0; kbk < 8; ++kbk) {
        const int cur = kbk & 1;
        if (kbk < 7) {
            const int t = kbk + 1, nb = cur ^ 1;
            gld16(&kb[hoQK + (size_t)(t*64 + tr0)*64 + sc*8], &Ks[nb][(2*w+0)*512]);
            gld16(&kb[hoQK + (size_t)(t*64 + tr1)*64 + sc*8], &Ks[nb][(2*w+1)*512]);
            gld16(&vT[hoV + (size_t)tr0*512 + t*64 + sc*8],   &Vs[nb][(2*w+0)*512]);
            gld16(&vT[hoV + (size_t)tr1*512 + t*64 + sc*8],   &Vs[nb][(2*w+1)*512]);
            asm volatile("s_waitcnt vmcnt(4)" ::: "memory");  // tile kbk landed; 4 prefetch in flight
        } else {
            asm volatile("s_waitcnt vmcnt(0)" ::: "memory");
        }
        __syncthreads();   // tile kbk visible to all waves

        // S = Q K^T   (scale pre-folded into q)
        f32x4_t sa[2][4] = {};
#pragma unroll
        for (int kk = 0; kk < 2; ++kk) {
            bf16x8_t kf[4];
#pragma unroll
            for (int nj = 0; nj < 4; ++nj)
                kf[nj] = *reinterpret_cast<const bf16x8_t*>(&Ks[cur][swz(nj*16 + l15, kk*4 + lhi)]);
#pragma unroll
            for (int mi = 0; mi < 2; ++mi)
#pragma unroll
                for (int nj = 0; nj < 4; ++nj)
                    sa[mi][nj] = __builtin_amdgcn_mfma_f32_16x16x32_bf16(qf[mi][kk], kf[nj], sa[mi][nj], 0, 0, 0);
        }

        // mask + per-row tile max
        float tmax[2][4];
#pragma unroll
        for (int mi = 0; mi < 2; ++mi)
#pragma unroll
            for (int i = 0; i < 4; ++i) tmax[mi][i] = -1e30f;

#pragma unroll
        for (int mi = 0; mi < 2; ++mi) {
#pragma unroll
            for (int i = 0; i < 4; ++i) {
                const int qrow = q0 + mi*16 + lhi*4 + i;
                const size_t mbase = ((size_t)bt*512 + qrow)*512 + kbk*64 + l15;
#pragma unroll
                for (int nj = 0; nj < 4; ++nj) {
                    const int mv = Mm[mbase + nj*16];
                    const float s = sa[mi][nj][i] + (float)mv * NEG;
                    sa[mi][nj][i] = s;
                    tmax[mi][i] = fmaxf(tmax[mi][i], s);
                }
            }
        }
#pragma unroll
        for (int d = 1; d < 16; d <<= 1)
#pragma unroll
            for (int mi = 0; mi < 2; ++mi)
#pragma unroll
                for (int i = 0; i < 4; ++i)
                    tmax[mi][i] = fmaxf(tmax[mi][i], __shfl_xor(tmax[mi][i], d));

        float corr[2][4], rs[2][4];
#pragma unroll
        for (int mi = 0; mi < 2; ++mi)
#pragma unroll
            for (int i = 0; i < 4; ++i) {
                const float mn = fmaxf(mrow[mi][i], tmax[mi][i]);
                corr[mi][i] = __expf(mrow[mi][i] - mn);
                mrow[mi][i] = mn;
                rs[mi][i] = 0.f;
            }

#pragma unroll
        for (int mi = 0; mi < 2; ++mi)
#pragma unroll
            for (int nj = 0; nj < 4; ++nj)
#pragma unroll
                for (int i = 0; i < 4; ++i) {
                    const float p = __expf(sa[mi][nj][i] - mrow[mi][i]);
                    sa[mi][nj][i] = p;
                    rs[mi][i] += p;
                }
#pragma unroll
        for (int d = 1; d < 16; d <<= 1)
#pragma unroll
            for (int mi = 0; mi < 2; ++mi)
#pragma unroll
                for (int i = 0; i < 4; ++i)
                    rs[mi][i] += __shfl_xor(rs[mi][i], d);

#pragma unroll
        for (int mi = 0; mi < 2; ++mi)
#pragma unroll
            for (int i = 0; i < 4; ++i)
                lrow[mi][i] = lrow[mi][i]*corr[mi][i] + rs[mi][i];

#pragma unroll
        for (int mi = 0; mi < 2; ++mi)
#pragma unroll
            for (int dj = 0; dj < 4; ++dj)
#pragma unroll
                for (int i = 0; i < 4; ++i)
                    of[mi][dj][i] *= corr[mi][i];

        // P -> LDS (swizzled) then re-read as A-fragments
#pragma unroll
        for (int mi = 0; mi < 2; ++mi)
#pragma unroll
            for (int nj = 0; nj < 4; ++nj)
#pragma unroll
                for (int i = 0; i < 4; ++i) {
                    const int prow = mi*16 + lhi*4 + i;
                    const int pcol = nj*16 + l15;
                    Ps[w][swz(prow, pcol >> 3) + (pcol & 7)] = f2b(sa[mi][nj][i]);
                }

        bf16x8_t pf[2][2];
#pragma unroll
        for (int mi = 0; mi < 2; ++mi)
#pragma unroll
            for (int kk = 0; kk < 2; ++kk)
                pf[mi][kk] = *reinterpret_cast<const bf16x8_t*>(&Ps[w][swz(mi*16 + l15, kk*4 + lhi)]);

#pragma unroll
        for (int kk = 0; kk < 2; ++kk) {
            bf16x8_t vf[4];
#pragma unroll
            for (int dj = 0; dj < 4; ++dj)
                vf[dj] = *reinterpret_cast<const bf16x8_t*>(&Vs[cur][swz(dj*16 + l15, kk*4 + lhi)]);
#pragma unroll
            for (int mi = 0; mi < 2; ++mi)
#pragma unroll
                for (int dj = 0; dj < 4; ++dj)
                    of[mi][dj] = __builtin_amdgcn_mfma_f32_16x16x32_bf16(pf[mi][kk], vf[dj], of[mi][dj], 0, 0, 0);
        }

        __syncthreads();   // all waves done reading buf[cur] before tile kbk+2 overwrites it
    }

#pragma unroll
    for (int mi = 0; mi < 2; ++mi)
#pragma unroll
        for (int i = 0; i < 4; ++i) {
            const int qrow = q0 + mi*16 + lhi*4 + i;
            const float inv = 1.f / lrow[mi][i];
#pragma unroll
            for (int dj = 0; dj < 4; ++dj)
                ob[((size_t)bt*512 + qrow)*512 + h*64 + dj*16 + l15] = f2b(of[mi][dj][i] * inv);
        }
}

// ---------------- GEMM2: out = A @ Wo^T + b (fp32 out) ----------------
__global__ __launch_bounds__(256) void gemm_out(
    const unsigned short* __restrict__ A,   // [24576][512] bf16
    const unsigned short* __restrict__ W,   // [512][512] bf16
    const float* __restrict__ bias,
    float* __restrict__ out)
{
    __shared__ unsigned short As[128*64];
    __shared__ unsigned short Bs[128*64];
    const int tid = threadIdx.x;
    const int lane = tid & 63;
    const int l15 = lane & 15, lhi = lane >> 4;
    const int wid = tid >> 6, wr = wid >> 1, wc = wid & 1;
    const int m0 = blockIdx.y * 128, n0 = blockIdx.x * 128;
    const int rA = lane >> 3;
    const int sc = (lane & 7) ^ rA;

    f32x4_t acc[4][4] = {};

    for (int k0 = 0; k0 < 512; k0 += 64) {
        __syncthreads();
#pragma unroll
        for (int j = 0; j < 4; ++j) {
            const int ch = 4*wid + j;
            const int gr = ch*8 + rA;
            gld16(&A[(size_t)(m0+gr)*512 + k0 + sc*8], &As[ch*512]);
            gld16(&W[(size_t)(n0+gr)*512 + k0 + sc*8], &Bs[ch*512]);
        }
        asm volatile("s_waitcnt vmcnt(0)" ::: "memory");
        __syncthreads();
#pragma unroll
        for (int kk = 0; kk < 2; ++kk) {
            bf16x8_t af[4], bfr[4];
#pragma unroll
            for (int x = 0; x < 4; ++x) {
                af[x]  = *reinterpret_cast<const bf16x8_t*>(&As[swz(wr*64 + x*16 + l15, kk*4 + lhi)]);
                bfr[x] = *reinterpret_cast<const bf16x8_t*>(&Bs[swz(wc*64 + x*16 + l15, kk*4 + lhi)]);
            }
#pragma unroll
            for (int mi = 0; mi < 4; ++mi)
#pragma unroll
                for (int nj = 0; nj < 4; ++nj)
                    acc[mi][nj] = __builtin_amdgcn_mfma_f32_16x16x32_bf16(af[mi], bfr[nj], acc[mi][nj], 0, 0, 0);
        }
    }

#pragma unroll
    for (int mi = 0; mi < 4; ++mi) {
#pragma unroll
        for (int nj = 0; nj < 4; ++nj) {
            const int gn = n0 + wc*64 + nj*16 + l15;
            const float bi = bias[gn];
#pragma unroll
            for (int i = 0; i < 4; ++i) {
                const int gm = m0 + wr*64 + mi*16 + lhi*4 + i;
                out[(size_t)gm*512 + gn] = acc[mi][nj][i] + bi;
            }
        }
    }
}

extern "C" void kernel_launch(void* const* d_in, const int* in_sizes, int n_in,
                              void* d_out, int out_size, void* d_ws, size_t ws_size,
                              hipStream_t stream) {
    (void)in_sizes; (void)n_in; (void)out_size; (void)ws_size;
    // setup_inputs order: V, K, Q, M, wx_w, wx_b, wo_w, wo_b  (V,K unused by reference)
    const float* Qin = (const float*)d_in[2];
    const int*   Mm  = (const int*)d_in[3];
    const float* wxw = (const float*)d_in[4];
    const float* wxb = (const float*)d_in[5];
    const float* wow = (const float*)d_in[6];
    const float* wob = (const float*)d_in[7];
    float* out = (float*)d_out;

    char* ws = (char*)d_ws;
    const size_t SZ_A  = (size_t)24576*512*2;   // Q bf16 / attn-out bf16 (reused)
    const size_t SZ_WX = (size_t)1536*512*2;
    const size_t SZ_WO = (size_t)512*512*2;
    const size_t SZ_H  = (size_t)48*8*512*64*2; // per q/k/vT buffer

    unsigned short* Abf  = (unsigned short*)(ws);
    unsigned short* Wxb  = (unsigned short*)(ws + SZ_A);
    unsigned short* Wob  = (unsigned short*)(ws + SZ_A + SZ_WX);
    unsigned short* qb   = (unsigned short*)(ws + SZ_A + SZ_WX + SZ_WO);
    unsigned short* kbuf = (unsigned short*)(ws + SZ_A + SZ_WX + SZ_WO + SZ_H);
    unsigned short* vT   = (unsigned short*)(ws + SZ_A + SZ_WX + SZ_WO + 2*SZ_H);
    unsigned short* attn = Abf;  // reuse: GEMM1 is done with Abf before attention writes

    cvt_kernel<<<(24576*512/4)/256, 256, 0, stream>>>(Qin, Abf, 24576*512/4);
    cvt_kernel<<<(1536*512/4)/256, 256, 0, stream>>>(wxw, Wxb, 1536*512/4);
    cvt_kernel<<<(512*512/4)/256, 256, 0, stream>>>(wow, Wob, 512*512/4);

    gemm_qkv<<<dim3(12, 192), 256, 0, stream>>>(Abf, Wxb, wxb, qb, kbuf, vT);
    attn_kernel<<<dim3(4, 8, 48), 256, 0, stream>>>(qb, kbuf, vT, Mm, attn);
    gemm_out<<<dim3(4, 192), 256, 0, stream>>>(attn, Wob, wob, out);
}